// Round 2
// baseline (446.574 us; speedup 1.0000x reference)
//
#include <hip/hip_runtime.h>
#include <cstdint>

#define TOPK 2000
#define NMS_THR 0.5f
#define NCLS 21
#define HSHIFT 14
#define HBINS (1u << 18)
#define CAND_CAP 4096
#define TPAD 2048  // padded TOPK for transposed mask

typedef unsigned long long u64;
typedef unsigned int u32;

// IoU exactly as reference get_iou. contract(off) to match numpy rounding.
__device__ __forceinline__ float iou_pair(float ax1, float ay1, float ax2, float ay2, float aarea,
                                          float bx1, float by1, float bx2, float by2, float barea) {
#pragma clang fp contract(off)
    float ltx = fmaxf(ax1, bx1), lty = fmaxf(ay1, by1);
    float rbx = fminf(ax2, bx2), rby = fminf(ay2, by2);
    float wx = fmaxf(rbx - ltx, 0.f), wy = fmaxf(rby - lty, 0.f);
    float inter = wx * wy;
    return inter / (aarea + barea - inter);
}

__global__ void k_zero(u32* __restrict__ hist, u32* __restrict__ meta) {
    int i = blockIdx.x * 256 + threadIdx.x;
    ((uint4*)hist)[i] = make_uint4(0u, 0u, 0u, 0u);  // grid sized so i*4 < HBINS
    if (i < 64) meta[i] = 0u;
}

// Per-proposal: softmax score+cls, decode selected-class box (clamped),
// score bits + histogram, GT IoU argmax, encode reg targets -> out rows 2000+.
__global__ __launch_bounds__(256) void k_main(
    const float* __restrict__ prop, const float* __restrict__ btp,
    const float* __restrict__ cls, const float* __restrict__ gt,
    const int* __restrict__ hptr, const int* __restrict__ wptr,
    float* __restrict__ out, float4* __restrict__ box_per,
    u32* __restrict__ score_bits, u32* __restrict__ hist,
    int N, int G) {
#pragma clang fp contract(off)
    __shared__ float4 sgt[256];
    __shared__ float sga[256];
    __shared__ float scls[256 * NCLS];
    int tid = threadIdx.x;
    for (int g = tid; g < G; g += 256) {
        float4 gb = ((const float4*)gt)[g];
        sgt[g] = gb;
        sga[g] = (gb.z - gb.x) * (gb.w - gb.y);
    }
    size_t base = (size_t)blockIdx.x * 256 * NCLS;
    size_t total = (size_t)N * NCLS;
    int cnt = (int)((total > base) ? ((total - base > (size_t)(256 * NCLS)) ? (size_t)(256 * NCLS)
                                                                            : (total - base))
                                   : (size_t)0);
    if (cnt == 256 * NCLS) {
        const float4* src = (const float4*)(cls + base);
        for (int u = tid; u < 256 * NCLS / 4; u += 256) ((float4*)scls)[u] = src[u];
    } else {
        for (int u = tid; u < cnt; u += 256) scls[u] = cls[base + u];
    }
    __syncthreads();

    int i = blockIdx.x * 256 + tid;
    if (i >= N) return;

    float W = (float)wptr[0], H = (float)hptr[0];
    float4 p = ((const float4*)prop)[i];
    float pw = p.z - p.x, ph = p.w - p.y;
    float pcx = p.x + 0.5f * pw, pcy = p.y + 0.5f * ph;

    const float* s = &scls[tid * NCLS];
    float m = s[0];
#pragma unroll
    for (int c = 1; c < NCLS; ++c) m = fmaxf(m, s[c]);
    float e[NCLS];
    float Z = 0.f;
#pragma unroll
    for (int c = 0; c < NCLS; ++c) {
        e[c] = expf(s[c] - m);
        Z += e[c];
    }
    float best = -1.f;
    int bc = 1;
#pragma unroll
    for (int c = 1; c < NCLS; ++c) {
        float pr = e[c] / Z;
        if (pr > best) { best = pr; bc = c; }
    }

    float4 t = ((const float4*)btp)[(size_t)i * NCLS + bc];
    float qcx = t.x * pw + pcx, qcy = t.y * ph + pcy;
    float qw = expf(t.z) * pw, qh = expf(t.w) * ph;
    float bx1 = fminf(fmaxf(qcx - 0.5f * qw, 0.f), W);
    float by1 = fminf(fmaxf(qcy - 0.5f * qh, 0.f), H);
    float bx2 = fminf(fmaxf(qcx + 0.5f * qw, 0.f), W);
    float by2 = fminf(fmaxf(qcy + 0.5f * qh, 0.f), H);
    box_per[i] = make_float4(bx1, by1, bx2, by2);

    u32 b = __float_as_uint(best);
    score_bits[i] = b;
    atomicAdd(&hist[b >> HSHIFT], 1u);

    float parea = pw * ph;
    float bestiou = -1.f;
    int bi = 0;
    for (int g = 0; g < G; ++g) {
        float4 gb = sgt[g];
        float v = iou_pair(gb.x, gb.y, gb.z, gb.w, sga[g], p.x, p.y, p.z, p.w, parea);
        if (v > bestiou) { bestiou = v; bi = g; }
    }
    float4 mg = sgt[bi];
    float gw = mg.z - mg.x, gh = mg.w - mg.y;
    float gcx = mg.x + 0.5f * gw, gcy = mg.y + 0.5f * gh;
    float4 rt = make_float4((gcx - pcx) / pw, (gcy - pcy) / ph, logf(gw / pw), logf(gh / ph));
    ((float4*)out)[TOPK + i] = rt;
}

// 1024 blocks x 256: coalesced per-256-bin chunk sums.
__global__ __launch_bounds__(256) void k_hsum(const u32* __restrict__ hist,
                                              u32* __restrict__ csum) {
    int b = blockIdx.x, t = threadIdx.x;
    u32 v = hist[(size_t)b * 256 + t];
#pragma unroll
    for (int o = 32; o; o >>= 1) v += __shfl_xor(v, o);
    __shared__ u32 ps[4];
    if ((t & 63) == 0) ps[t >> 6] = v;
    __syncthreads();
    if (t == 0) csum[b] = ps[0] + ps[1] + ps[2] + ps[3];
}

// One small block: suffix-scan chunk sums, then the winning 256-bin chunk.
__global__ __launch_bounds__(1024) void k_scan2(const u32* __restrict__ csum,
                                                const u32* __restrict__ hist,
                                                u32* __restrict__ meta) {
    __shared__ u32 S[1024];
    __shared__ u32 sh_tc, sh_E;
    int t = threadIdx.x;
    u32 acc = csum[t];
    S[t] = acc;
    __syncthreads();
    for (int off = 1; off < 1024; off <<= 1) {
        u32 v = (t + off < 1024) ? S[t + off] : 0u;
        __syncthreads();
        S[t] += v;
        __syncthreads();
    }
    u32 suff = S[t];
    u32 E = suff - acc;
    if (suff >= TOPK && E < TOPK) { sh_tc = (u32)t; sh_E = E; }
    __syncthreads();
    u32 tc = sh_tc, E0 = sh_E;
    u32 h = (t < 256) ? hist[(size_t)tc * 256 + t] : 0u;
    __syncthreads();
    S[t] = (t < 256) ? h : 0u;
    __syncthreads();
    for (int off = 1; off < 256; off <<= 1) {
        u32 v = (t + off < 1024) ? S[t + off] : 0u;
        __syncthreads();
        S[t] += v;
        __syncthreads();
    }
    if (t < 256) {
        u32 tot = E0 + S[t];
        if (tot >= TOPK && (tot - h) < TOPK) meta[0] = tc * 256u + (u32)t;
    }
}

__global__ __launch_bounds__(256) void k_compact(const u32* __restrict__ score_bits,
                                                 const u32* __restrict__ meta, u32* __restrict__ cnt,
                                                 u64* __restrict__ keys, int N) {
    int i = blockIdx.x * 256 + threadIdx.x;
    if (i >= N) return;
    u32 b = score_bits[i];
    if ((b >> HSHIFT) >= meta[0]) {
        u32 pos = atomicAdd(cnt, 1u);
        if (pos < CAND_CAP) keys[pos] = ((u64)b << 32) | (u32)(~(u32)i);
    }
}

// Rank-sort: keys unique (idx in low bits) -> rank is a perfect permutation.
// LDS-broadcast inner loop; exact lax.top_k order (score desc, index asc).
__global__ __launch_bounds__(1024) void k_rank(const u64* __restrict__ keys,
                                               const u32* __restrict__ meta,
                                               const float4* __restrict__ box_per,
                                               float4* __restrict__ topbox) {
    __shared__ u64 sk[CAND_CAP];
    int t = threadIdx.x;
    u32 M = meta[1];
    if (M > CAND_CAP) M = CAND_CAP;
    for (int u = t; u < (int)M; u += 1024) sk[u] = keys[u];
    __syncthreads();
    for (int idx = t; idx < (int)M; idx += 1024) {
        u64 k = sk[idx];
        u32 r = 0;
        int j = 0;
        for (; j + 4 <= (int)M; j += 4) {
            r += (sk[j] > k);
            r += (sk[j + 1] > k);
            r += (sk[j + 2] > k);
            r += (sk[j + 3] > k);
        }
        for (; j < (int)M; ++j) r += (sk[j] > k);
        if (r < TOPK) topbox[r] = box_per[~(u32)(k & 0xffffffffull)];
    }
}

// Transposed suppression mask: maskT[w*TPAD + i] = word w of row i
// (bit jj set iff j=w*64+jj > i, j<TOPK, iou>thr). Coalesced writes,
// wave-uniform topbox[j] broadcast loads.
__global__ __launch_bounds__(256) void k_mask(const float4* __restrict__ topbox,
                                              u64* __restrict__ maskT) {
#pragma clang fp contract(off)
    int gid = blockIdx.x * 256 + threadIdx.x;  // 32 * TPAD threads
    int w = gid >> 11, i = gid & (TPAD - 1);
    u64 m = 0;
    int j0 = w << 6;
    if (i < TOPK && j0 + 63 > i) {
        float4 a = topbox[i];
        float aarea = (a.z - a.x) * (a.w - a.y);
        for (int jj = 0; jj < 64; ++jj) {
            int j = j0 + jj;
            if (j < TOPK && j > i) {
                float4 b = topbox[j];
                float barea = (b.z - b.x) * (b.w - b.y);
                float v = iou_pair(a.x, a.y, a.z, a.w, aarea, b.x, b.y, b.z, b.w, barea);
                if (v > NMS_THR) m |= (1ull << jj);
            }
        }
    }
    maskT[(size_t)w * TPAD + i] = m;
}

// Greedy NMS. Stage A: wave 0 does the serial 64-bit recurrence with one
// coalesced column load + v_readlane (no per-step memory latency).
// Stage B: 16 waves apply finalized chunk c to later words g via coalesced
// loads (issued BEFORE stage A so latency hides) + shfl-OR reduction.
__global__ __launch_bounds__(1024) void k_nms(const u64* __restrict__ maskT,
                                              const float4* __restrict__ topbox,
                                              float* __restrict__ out) {
    __shared__ u64 removed[32];
    int t = threadIdx.x;
    int wave = t >> 6, lane = t & 63;
    if (t < 32) removed[t] = 0ull;
    __syncthreads();
    int g0 = wave * 2, g1 = wave * 2 + 1;
    for (int c = 0; c < 32; ++c) {
        // prefetch stage-B data (independent of removed[])
        u64 mv0 = 0, mv1 = 0;
        if (g0 > c) mv0 = maskT[(size_t)g0 * TPAD + (c << 6) + lane];
        if (g1 > c) mv1 = maskT[(size_t)g1 * TPAD + (c << 6) + lane];
        if (wave == 0) {
            u64 colv = maskT[(size_t)c * TPAD + (c << 6) + lane];
            u32 clo = (u32)colv, chi = (u32)(colv >> 32);
            u64 rw = removed[c];
#pragma unroll
            for (int l = 0; l < 64; ++l) {
                u64 bl = ((u64)__builtin_amdgcn_readlane(chi, l) << 32) |
                         (u64)__builtin_amdgcn_readlane(clo, l);
                if (!((rw >> l) & 1ull)) rw |= bl;
            }
            if (lane == 0) removed[c] = rw;
        }
        __syncthreads();
        u64 rw = removed[c];
        bool sup = (rw >> lane) & 1ull;
        u64 a0 = sup ? 0ull : mv0;
        u64 a1 = sup ? 0ull : mv1;
#pragma unroll
        for (int o = 32; o; o >>= 1) {
            a0 |= __shfl_xor(a0, o);
            a1 |= __shfl_xor(a1, o);
        }
        if (lane == 0) {
            if (g0 > c) removed[g0] |= a0;
            if (g1 > c) removed[g1] |= a1;
        }
        __syncthreads();
    }
    for (int r = t; r < TOPK; r += 1024) {
        bool sup = (removed[r >> 6] >> (r & 63)) & 1ull;
        float4 b = topbox[r];
        ((float4*)out)[r] = sup ? make_float4(0.f, 0.f, 0.f, 0.f) : b;
    }
}

extern "C" void kernel_launch(void* const* d_in, const int* in_sizes, int n_in,
                              void* d_out, int out_size, void* d_ws, size_t ws_size,
                              hipStream_t stream) {
    const float* prop = (const float*)d_in[0];
    const float* btp = (const float*)d_in[1];
    const float* cls = (const float*)d_in[2];
    const float* gt = (const float*)d_in[3];
    const int* hptr = (const int*)d_in[4];
    const int* wptr = (const int*)d_in[5];
    float* out = (float*)d_out;
    int N = in_sizes[0] / 4;
    int G = in_sizes[3] / 4;
    if (G > 256) G = 256;

    char* ws = (char*)d_ws;
    size_t o = 0;
    u32* hist = (u32*)(ws + o);       o += (size_t)HBINS * 4;
    u32* csum = (u32*)(ws + o);       o += 1024 * 4;
    u32* meta = (u32*)(ws + o);       o += 256;
    u32* score_bits = (u32*)(ws + o); o += (((size_t)N * 4 + 255) & ~(size_t)255);
    u64* keys = (u64*)(ws + o);       o += (size_t)CAND_CAP * 8;
    float4* box_per = (float4*)(ws + o); o += (size_t)N * 16;
    float4* topbox = (float4*)(ws + o);  o += (size_t)TPAD * 16;
    u64* maskT = (u64*)(ws + o);      o += (size_t)32 * TPAD * 8;
    (void)o; (void)ws_size; (void)n_in; (void)out_size;

    int nb = (N + 255) / 256;
    k_zero<<<HBINS / 4 / 256, 256, 0, stream>>>(hist, meta);
    k_main<<<nb, 256, 0, stream>>>(prop, btp, cls, gt, hptr, wptr, out, box_per, score_bits,
                                   hist, N, G);
    k_hsum<<<1024, 256, 0, stream>>>(hist, csum);
    k_scan2<<<1, 1024, 0, stream>>>(csum, hist, meta);
    k_compact<<<nb, 256, 0, stream>>>(score_bits, meta, meta + 1, keys, N);
    k_rank<<<1, 1024, 0, stream>>>(keys, meta, box_per, topbox);
    k_mask<<<(32 * TPAD) / 256, 256, 0, stream>>>(topbox, maskT);
    k_nms<<<1, 1024, 0, stream>>>(maskT, topbox, out);
}

// Round 3
// 313.675 us; speedup vs baseline: 1.4237x; 1.4237x over previous
//
#include <hip/hip_runtime.h>
#include <cstdint>

#define TOPK 2000
#define NMS_THR 0.5f
#define NCLS 21
#define HSHIFT 14
#define HBINS (1u << 18)
#define CAND_CAP 4096
#define TPAD 2048

typedef unsigned long long u64;
typedef unsigned int u32;

// IoU exactly as reference get_iou. contract(off) to match numpy rounding.
__device__ __forceinline__ float iou_pair(float ax1, float ay1, float ax2, float ay2, float aarea,
                                          float bx1, float by1, float bx2, float by2, float barea) {
#pragma clang fp contract(off)
    float ltx = fmaxf(ax1, bx1), lty = fmaxf(ay1, by1);
    float rbx = fminf(ax2, bx2), rby = fminf(ay2, by2);
    float wx = fmaxf(rbx - ltx, 0.f), wy = fmaxf(rby - lty, 0.f);
    float inter = wx * wy;
    return inter / (aarea + barea - inter);
}

__global__ void k_zero(u32* __restrict__ hist, u32* __restrict__ meta) {
    int i = blockIdx.x * 256 + threadIdx.x;
    ((uint4*)hist)[i] = make_uint4(0u, 0u, 0u, 0u);
    if (i < 64) meta[i] = 0u;
}

// Per-proposal: softmax score+cls, decode selected-class box (clamped),
// score bits + histogram, GT IoU argmax, encode reg targets -> out rows 2000+.
__global__ __launch_bounds__(256) void k_main(
    const float* __restrict__ prop, const float* __restrict__ btp,
    const float* __restrict__ cls, const float* __restrict__ gt,
    const int* __restrict__ hptr, const int* __restrict__ wptr,
    float* __restrict__ out, float4* __restrict__ box_per,
    u32* __restrict__ score_bits, u32* __restrict__ hist,
    int N, int G) {
#pragma clang fp contract(off)
    __shared__ float4 sgt[256];
    __shared__ float sga[256];
    __shared__ float scls[256 * NCLS];
    int tid = threadIdx.x;
    for (int g = tid; g < G; g += 256) {
        float4 gb = ((const float4*)gt)[g];
        sgt[g] = gb;
        sga[g] = (gb.z - gb.x) * (gb.w - gb.y);
    }
    size_t base = (size_t)blockIdx.x * 256 * NCLS;
    size_t total = (size_t)N * NCLS;
    int cnt = (int)((total > base) ? ((total - base > (size_t)(256 * NCLS)) ? (size_t)(256 * NCLS)
                                                                            : (total - base))
                                   : (size_t)0);
    if (cnt == 256 * NCLS) {
        const float4* src = (const float4*)(cls + base);
        for (int u = tid; u < 256 * NCLS / 4; u += 256) ((float4*)scls)[u] = src[u];
    } else {
        for (int u = tid; u < cnt; u += 256) scls[u] = cls[base + u];
    }
    __syncthreads();

    int i = blockIdx.x * 256 + tid;
    if (i >= N) return;

    float W = (float)wptr[0], H = (float)hptr[0];
    float4 p = ((const float4*)prop)[i];
    float pw = p.z - p.x, ph = p.w - p.y;
    float pcx = p.x + 0.5f * pw, pcy = p.y + 0.5f * ph;

    const float* s = &scls[tid * NCLS];
    float m = s[0];
#pragma unroll
    for (int c = 1; c < NCLS; ++c) m = fmaxf(m, s[c]);
    float e[NCLS];
    float Z = 0.f;
#pragma unroll
    for (int c = 0; c < NCLS; ++c) {
        e[c] = expf(s[c] - m);
        Z += e[c];
    }
    float best = -1.f;
    int bc = 1;
#pragma unroll
    for (int c = 1; c < NCLS; ++c) {
        float pr = e[c] / Z;
        if (pr > best) { best = pr; bc = c; }
    }

    float4 t = ((const float4*)btp)[(size_t)i * NCLS + bc];
    float qcx = t.x * pw + pcx, qcy = t.y * ph + pcy;
    float qw = expf(t.z) * pw, qh = expf(t.w) * ph;
    float bx1 = fminf(fmaxf(qcx - 0.5f * qw, 0.f), W);
    float by1 = fminf(fmaxf(qcy - 0.5f * qh, 0.f), H);
    float bx2 = fminf(fmaxf(qcx + 0.5f * qw, 0.f), W);
    float by2 = fminf(fmaxf(qcy + 0.5f * qh, 0.f), H);
    box_per[i] = make_float4(bx1, by1, bx2, by2);

    u32 b = __float_as_uint(best);
    score_bits[i] = b;
    atomicAdd(&hist[b >> HSHIFT], 1u);

    float parea = pw * ph;
    float bestiou = -1.f;
    int bi = 0;
    for (int g = 0; g < G; ++g) {
        float4 gb = sgt[g];
        float v = iou_pair(gb.x, gb.y, gb.z, gb.w, sga[g], p.x, p.y, p.z, p.w, parea);
        if (v > bestiou) { bestiou = v; bi = g; }
    }
    float4 mg = sgt[bi];
    float gw = mg.z - mg.x, gh = mg.w - mg.y;
    float gcx = mg.x + 0.5f * gw, gcy = mg.y + 0.5f * gh;
    float4 rt = make_float4((gcx - pcx) / pw, (gcy - pcy) / ph, logf(gw / pw), logf(gh / ph));
    ((float4*)out)[TOPK + i] = rt;
}

// 1024 blocks x 256: coalesced per-256-bin chunk sums.
__global__ __launch_bounds__(256) void k_hsum(const u32* __restrict__ hist,
                                              u32* __restrict__ csum) {
    int b = blockIdx.x, t = threadIdx.x;
    u32 v = hist[(size_t)b * 256 + t];
#pragma unroll
    for (int o = 32; o; o >>= 1) v += __shfl_xor(v, o);
    __shared__ u32 ps[4];
    if ((t & 63) == 0) ps[t >> 6] = v;
    __syncthreads();
    if (t == 0) csum[b] = ps[0] + ps[1] + ps[2] + ps[3];
}

// One small block: suffix-scan chunk sums, then the winning 256-bin chunk.
__global__ __launch_bounds__(1024) void k_scan2(const u32* __restrict__ csum,
                                                const u32* __restrict__ hist,
                                                u32* __restrict__ meta) {
    __shared__ u32 S[1024];
    __shared__ u32 sh_tc, sh_E;
    int t = threadIdx.x;
    u32 acc = csum[t];
    S[t] = acc;
    __syncthreads();
    for (int off = 1; off < 1024; off <<= 1) {
        u32 v = (t + off < 1024) ? S[t + off] : 0u;
        __syncthreads();
        S[t] += v;
        __syncthreads();
    }
    u32 suff = S[t];
    u32 E = suff - acc;
    if (suff >= TOPK && E < TOPK) { sh_tc = (u32)t; sh_E = E; }
    __syncthreads();
    u32 tc = sh_tc, E0 = sh_E;
    u32 h = (t < 256) ? hist[(size_t)tc * 256 + t] : 0u;
    __syncthreads();
    S[t] = (t < 256) ? h : 0u;
    __syncthreads();
    for (int off = 1; off < 256; off <<= 1) {
        u32 v = (t + off < 1024) ? S[t + off] : 0u;
        __syncthreads();
        S[t] += v;
        __syncthreads();
    }
    if (t < 256) {
        u32 tot = E0 + S[t];
        if (tot >= TOPK && (tot - h) < TOPK) meta[0] = tc * 256u + (u32)t;
    }
}

__global__ __launch_bounds__(256) void k_compact(const u32* __restrict__ score_bits,
                                                 const u32* __restrict__ meta, u32* __restrict__ cnt,
                                                 u64* __restrict__ keys, int N) {
    int i = blockIdx.x * 256 + threadIdx.x;
    if (i >= N) return;
    u32 b = score_bits[i];
    if ((b >> HSHIFT) >= meta[0]) {
        u32 pos = atomicAdd(cnt, 1u);
        if (pos < CAND_CAP) keys[pos] = ((u64)b << 32) | (u32)(~(u32)i);
    }
}

// Rank-sort, 16 blocks. Tile keys 64-at-a-time into registers; broadcast via
// v_readlane (VALU) instead of uniform ds_read (which serialized on one CU's
// LDS pipe last round). Keys unique -> ranks form a permutation.
__global__ __launch_bounds__(256) void k_rank(const u64* __restrict__ keys,
                                              const u32* __restrict__ meta,
                                              const float4* __restrict__ box_per,
                                              float4* __restrict__ topbox) {
    __shared__ u64 sk[CAND_CAP];
    int t = threadIdx.x;
    u32 M = meta[1];
    if (M > CAND_CAP) M = CAND_CAP;
    u32 Mp = (M + 63u) & ~63u;
    for (int u = t; u < (int)Mp; u += 256) sk[u] = (u < (int)M) ? keys[u] : 0ull;
    __syncthreads();
    int idx = blockIdx.x * 256 + t;
    u64 k = (idx < (int)M) ? sk[idx] : ~0ull;
    u32 r = 0;
    int lane = t & 63;
    for (int j0 = 0; j0 < (int)Mp; j0 += 64) {
        u64 tv = sk[j0 + lane];
        u32 tlo = (u32)tv, thi = (u32)(tv >> 32);
#pragma unroll
        for (int l = 0; l < 64; ++l) {
            u64 kj = ((u64)(u32)__builtin_amdgcn_readlane(thi, l) << 32) |
                     (u64)(u32)__builtin_amdgcn_readlane(tlo, l);
            r += (kj > k) ? 1u : 0u;
        }
    }
    if (idx < (int)M && r < TOPK) topbox[r] = box_per[~(u32)(k & 0xffffffffull)];
}

// Suppression mask, ROW-major: mask[i*32+w] bit jj set iff j=w*64+jj>i, j<TOPK,
// iou>thr. w is block-uniform (topbox[j] stays a broadcast load); writes are
// strided (accepted: buys k_nms coalesced streaming reads).
__global__ __launch_bounds__(256) void k_mask(const float4* __restrict__ topbox,
                                              u64* __restrict__ mask) {
#pragma clang fp contract(off)
    int gid = blockIdx.x * 256 + threadIdx.x;  // 32 * TPAD threads
    int w = gid >> 11, i = gid & (TPAD - 1);
    u64 m = 0;
    int j0 = w << 6;
    if (i < TOPK && j0 + 63 > i) {
        float4 a = topbox[i];
        float aarea = (a.z - a.x) * (a.w - a.y);
        for (int jj = 0; jj < 64; ++jj) {
            int j = j0 + jj;
            if (j < TOPK && j > i) {
                float4 b = topbox[j];
                float barea = (b.z - b.x) * (b.w - b.y);
                float v = iou_pair(a.x, a.y, a.z, a.w, aarea, b.x, b.y, b.z, b.w, barea);
                if (v > NMS_THR) m |= (1ull << jj);
            }
        }
    }
    mask[(size_t)i * 32 + w] = m;
}

// Greedy NMS: ONE serial wave, no barriers in the recurrence. Lane w holds
// removed word w in registers. Per row: coalesced 256B row load (prefetched 64
// rows ahead), v_readlane keep-bit test, wave-wide masked OR. Waves 1-3 just
// help write the output.
__global__ __launch_bounds__(256) void k_nms(const u64* __restrict__ mask,
                                             const float4* __restrict__ topbox,
                                             float* __restrict__ out) {
    __shared__ u64 srem[32];
    int t = threadIdx.x;
    if (t < 64) {
        int lw = t & 31;
        u32 rlo = 0, rhi = 0;
        u64 ring[64];
#pragma unroll
        for (int p = 0; p < 64; ++p) ring[p] = mask[(size_t)p * 32 + lw];
        for (int c = 0; c < 32; ++c) {
#pragma unroll
            for (int l = 0; l < 64; ++l) {
                int i = c * 64 + l;
                u64 row = ring[l];
                int ip = (i + 64) & (TPAD - 1);  // wraps on last chunk; data unused
                ring[l] = mask[(size_t)ip * 32 + lw];
                u32 h = (l < 32) ? (u32)__builtin_amdgcn_readlane(rlo, c)
                                 : (u32)__builtin_amdgcn_readlane(rhi, c);
                u32 keep = ((h >> (l & 31)) & 1u) ^ 1u;
                u32 mk = 0u - keep;  // all-ones if keep
                rlo |= (u32)row & mk;
                rhi |= (u32)(row >> 32) & mk;
            }
        }
        if (t < 32) srem[t] = ((u64)rhi << 32) | rlo;
    }
    __syncthreads();
    for (int r = t; r < TOPK; r += 256) {
        bool sup = (srem[r >> 6] >> (r & 63)) & 1ull;
        float4 b = topbox[r];
        ((float4*)out)[r] = sup ? make_float4(0.f, 0.f, 0.f, 0.f) : b;
    }
}

extern "C" void kernel_launch(void* const* d_in, const int* in_sizes, int n_in,
                              void* d_out, int out_size, void* d_ws, size_t ws_size,
                              hipStream_t stream) {
    const float* prop = (const float*)d_in[0];
    const float* btp = (const float*)d_in[1];
    const float* cls = (const float*)d_in[2];
    const float* gt = (const float*)d_in[3];
    const int* hptr = (const int*)d_in[4];
    const int* wptr = (const int*)d_in[5];
    float* out = (float*)d_out;
    int N = in_sizes[0] / 4;
    int G = in_sizes[3] / 4;
    if (G > 256) G = 256;

    char* ws = (char*)d_ws;
    size_t o = 0;
    u32* hist = (u32*)(ws + o);       o += (size_t)HBINS * 4;
    u32* csum = (u32*)(ws + o);       o += 1024 * 4;
    u32* meta = (u32*)(ws + o);       o += 256;
    u32* score_bits = (u32*)(ws + o); o += (((size_t)N * 4 + 255) & ~(size_t)255);
    u64* keys = (u64*)(ws + o);       o += (size_t)CAND_CAP * 8;
    float4* box_per = (float4*)(ws + o); o += (size_t)N * 16;
    float4* topbox = (float4*)(ws + o);  o += (size_t)TPAD * 16;
    u64* mask = (u64*)(ws + o);       o += (size_t)TPAD * 32 * 8;
    (void)o; (void)ws_size; (void)n_in; (void)out_size;

    int nb = (N + 255) / 256;
    k_zero<<<HBINS / 4 / 256, 256, 0, stream>>>(hist, meta);
    k_main<<<nb, 256, 0, stream>>>(prop, btp, cls, gt, hptr, wptr, out, box_per, score_bits,
                                   hist, N, G);
    k_hsum<<<1024, 256, 0, stream>>>(hist, csum);
    k_scan2<<<1, 1024, 0, stream>>>(csum, hist, meta);
    k_compact<<<nb, 256, 0, stream>>>(score_bits, meta, meta + 1, keys, N);
    k_rank<<<CAND_CAP / 256, 256, 0, stream>>>(keys, meta, box_per, topbox);
    k_mask<<<(32 * TPAD) / 256, 256, 0, stream>>>(topbox, mask);
    k_nms<<<1, 256, 0, stream>>>(mask, topbox, out);
}